// Round 1
// baseline (1522.792 us; speedup 1.0000x reference)
//
#include <hip/hip_runtime.h>
#include <math.h>

#define NN 50000
#define NE 800000
#define NR 16

// ---------------------------------------------------------------------------
// K1: rel_w[r,i,o] = sum_b w_comp[r,b] * weight[b,i,o]          (16x32x32)
//     aproj[t,j]  = A_b[j] + sum_k attn_emb[t,k] * A_w[64+k, j] (16x32)
// ---------------------------------------------------------------------------
__global__ void k_prep(const float* __restrict__ weight, const float* __restrict__ w_comp,
                       const float* __restrict__ A_w, const float* __restrict__ A_b,
                       const float* __restrict__ attn_emb,
                       float* __restrict__ relw, float* __restrict__ aproj) {
    int gid = blockIdx.x * blockDim.x + threadIdx.x;
    if (gid < 16 * 1024) {
        int r = gid >> 10, rest = gid & 1023;
        float acc = 0.f;
#pragma unroll
        for (int b = 0; b < 4; b++) acc += w_comp[r * 4 + b] * weight[b * 1024 + rest];
        relw[gid] = acc;
    }
    if (gid < 16 * 32) {
        int t = gid >> 5, j = gid & 31;
        float acc = A_b[j];
#pragma unroll
        for (int k = 0; k < 32; k++) acc += attn_emb[t * 32 + k] * A_w[(64 + k) * 32 + j];
        aproj[gid] = acc;
    }
}

// ---------------------------------------------------------------------------
// K2: init_fea[i,:] = concat(feat[i], embed[idx[i]]) @ T ; store to out[i,0,:]
// One node per lane; T streamed through SGPRs (uniform address).
// ---------------------------------------------------------------------------
__global__ void k_init(const float* __restrict__ feat, const float* __restrict__ emb,
                       const float* __restrict__ T, const int* __restrict__ idx,
                       float* __restrict__ out) {
    int i = blockIdx.x * blockDim.x + threadIdx.x;
    if (i >= NN) return;
    float v[32], acc[32];
#pragma unroll
    for (int o = 0; o < 32; o++) acc[o] = 0.f;
    const float4* fp = (const float4*)(feat + (size_t)i * 32);
#pragma unroll
    for (int q = 0; q < 8; q++) {
        float4 f = fp[q];
        v[4 * q] = f.x; v[4 * q + 1] = f.y; v[4 * q + 2] = f.z; v[4 * q + 3] = f.w;
    }
#pragma unroll
    for (int d = 0; d < 32; d++) {
        float xd = v[d];
#pragma unroll
        for (int o = 0; o < 32; o++) acc[o] += xd * T[d * 32 + o];
    }
    int row = idx[i];
    const float4* ep = (const float4*)(emb + (size_t)row * 32);
#pragma unroll
    for (int q = 0; q < 8; q++) {
        float4 f = ep[q];
        v[4 * q] = f.x; v[4 * q + 1] = f.y; v[4 * q + 2] = f.z; v[4 * q + 3] = f.w;
    }
#pragma unroll
    for (int d = 0; d < 32; d++) {
        float xd = v[d];
#pragma unroll
        for (int o = 0; o < 32; o++) acc[o] += xd * T[(32 + d) * 32 + o];
    }
    float4* op = (float4*)(out + (size_t)i * 64);
#pragma unroll
    for (int q = 0; q < 8; q++) {
        float4 f;
        f.x = acc[4 * q]; f.y = acc[4 * q + 1]; f.z = acc[4 * q + 2]; f.w = acc[4 * q + 3];
        op[q] = f;
    }
}

// ---------------------------------------------------------------------------
// K3: per-type histogram (LDS-local then one global atomic per block per bin)
// ---------------------------------------------------------------------------
__global__ void k_hist(const int* __restrict__ et, int* __restrict__ counts) {
    __shared__ int lc[NR];
    if (threadIdx.x < NR) lc[threadIdx.x] = 0;
    __syncthreads();
    for (int e = blockIdx.x * blockDim.x + threadIdx.x; e < NE; e += gridDim.x * blockDim.x)
        atomicAdd(&lc[et[e]], 1);
    __syncthreads();
    if (threadIdx.x < NR) atomicAdd(&counts[threadIdx.x], lc[threadIdx.x]);
}

// K4: exclusive prefix over 16 bins; init cursors
__global__ void k_prefix(const int* __restrict__ counts, int* __restrict__ off,
                         int* __restrict__ cursor) {
    if (threadIdx.x == 0 && blockIdx.x == 0) {
        int acc = 0;
        for (int t = 0; t < NR; t++) {
            off[t] = acc;
            cursor[t] = acc;
            acc += counts[t];
        }
        off[NR] = acc;
    }
}

// ---------------------------------------------------------------------------
// K5: two-pass block scatter into type-sorted src/dst arrays
// ---------------------------------------------------------------------------
__global__ void k_scatter(const int* __restrict__ es, const int* __restrict__ ed,
                          const int* __restrict__ et, int* __restrict__ cursor,
                          int* __restrict__ ssrc, int* __restrict__ sdst) {
    const int chunk = (NE + gridDim.x - 1) / gridDim.x;
    const int start = blockIdx.x * chunk;
    const int end = min(start + chunk, NE);
    __shared__ int lc[NR], lb[NR];
    if (threadIdx.x < NR) lc[threadIdx.x] = 0;
    __syncthreads();
    for (int e = start + threadIdx.x; e < end; e += blockDim.x)
        atomicAdd(&lc[et[e]], 1);
    __syncthreads();
    if (threadIdx.x < NR) {
        lb[threadIdx.x] = atomicAdd(&cursor[threadIdx.x], lc[threadIdx.x]);
        lc[threadIdx.x] = 0;
    }
    __syncthreads();
    for (int e = start + threadIdx.x; e < end; e += blockDim.x) {
        int t = et[e];
        int p = atomicAdd(&lc[t], 1);
        int q = lb[t] + p;
        ssrc[q] = es[e];
        sdst[q] = ed[e];
    }
}

// ---------------------------------------------------------------------------
// K6: edge kernel. blockIdx.x = relation type (uniform) -> W_t / attn bias are
// SGPR-streamed. One edge per lane; x,y gathered as float4 from out[:,0,:].
// Scatter a*msg into out[:,1,:] with HW f32 atomics.
// ---------------------------------------------------------------------------
__global__ void __launch_bounds__(256) k_edge(
    const float* __restrict__ outr, const float* __restrict__ relw,
    const float* __restrict__ aproj, const float* __restrict__ A_w,
    const float* __restrict__ B_w, const float* __restrict__ B_b,
    const int* __restrict__ off, const int* __restrict__ ssrc,
    const int* __restrict__ sdst, float* __restrict__ outw) {
    const int t = blockIdx.x;
    const int s0 = off[t], s1 = off[t + 1];
    const float* Wt = relw + t * 1024;
    const float* AP = aproj + t * 32;
    const float bb = B_b[0];
    for (int base = s0 + blockIdx.y * blockDim.x; base < s1; base += gridDim.y * blockDim.x) {
        int e = base + threadIdx.x;
        if (e < s1) {
            int src = ssrc[e], dst = sdst[e];
            float v[32], msg[32], hid[32];
            const float4* xp = (const float4*)(outr + (size_t)src * 64);
#pragma unroll
            for (int q = 0; q < 8; q++) {
                float4 f = xp[q];
                v[4 * q] = f.x; v[4 * q + 1] = f.y; v[4 * q + 2] = f.z; v[4 * q + 3] = f.w;
            }
#pragma unroll
            for (int o = 0; o < 32; o++) msg[o] = 0.f;
#pragma unroll
            for (int j = 0; j < 32; j++) hid[j] = AP[j];
#pragma unroll
            for (int d = 0; d < 32; d++) {
                float xd = v[d];
#pragma unroll
                for (int o = 0; o < 32; o++) msg[o] += xd * Wt[d * 32 + o];
#pragma unroll
                for (int j = 0; j < 32; j++) hid[j] += xd * A_w[d * 32 + j];
            }
            const float4* yp = (const float4*)(outr + (size_t)dst * 64);
#pragma unroll
            for (int q = 0; q < 8; q++) {
                float4 f = yp[q];
                v[4 * q] = f.x; v[4 * q + 1] = f.y; v[4 * q + 2] = f.z; v[4 * q + 3] = f.w;
            }
#pragma unroll
            for (int d = 0; d < 32; d++) {
                float yd = v[d];
#pragma unroll
                for (int j = 0; j < 32; j++) hid[j] += yd * A_w[(32 + d) * 32 + j];
            }
            float z = bb;
#pragma unroll
            for (int j = 0; j < 32; j++) z += fmaxf(hid[j], 0.f) * B_w[j];
            float a = 1.f / (1.f + __expf(-z));
            float* ag = outw + (size_t)dst * 64 + 32;
#pragma unroll
            for (int o = 0; o < 32; o++) unsafeAtomicAdd(ag + o, a * msg[o]);
        }
    }
}

// ---------------------------------------------------------------------------
// K7: h = relu(init_fea @ self_loop_W + agg), in place on out[:,1,:]
// ---------------------------------------------------------------------------
__global__ void k_final(const float* __restrict__ S, float* __restrict__ out) {
    int i = blockIdx.x * blockDim.x + threadIdx.x;
    if (i >= NN) return;
    float v[32], acc[32];
    const float4* xp = (const float4*)(out + (size_t)i * 64);
#pragma unroll
    for (int q = 0; q < 8; q++) {
        float4 f = xp[q];
        v[4 * q] = f.x; v[4 * q + 1] = f.y; v[4 * q + 2] = f.z; v[4 * q + 3] = f.w;
    }
    const float4* ap = (const float4*)(out + (size_t)i * 64 + 32);
#pragma unroll
    for (int q = 0; q < 8; q++) {
        float4 f = ap[q];
        acc[4 * q] = f.x; acc[4 * q + 1] = f.y; acc[4 * q + 2] = f.z; acc[4 * q + 3] = f.w;
    }
#pragma unroll
    for (int d = 0; d < 32; d++) {
        float xd = v[d];
#pragma unroll
        for (int o = 0; o < 32; o++) acc[o] += xd * S[d * 32 + o];
    }
    float4* op = (float4*)(out + (size_t)i * 64 + 32);
#pragma unroll
    for (int q = 0; q < 8; q++) {
        float4 f;
        f.x = fmaxf(acc[4 * q], 0.f);
        f.y = fmaxf(acc[4 * q + 1], 0.f);
        f.z = fmaxf(acc[4 * q + 2], 0.f);
        f.w = fmaxf(acc[4 * q + 3], 0.f);
        op[q] = f;
    }
}

extern "C" void kernel_launch(void* const* d_in, const int* in_sizes, int n_in,
                              void* d_out, int out_size, void* d_ws, size_t ws_size,
                              hipStream_t stream) {
    const float* feat      = (const float*)d_in[0];
    const float* embed     = (const float*)d_in[1];
    const float* transform = (const float*)d_in[2];
    const float* weight    = (const float*)d_in[3];
    const float* w_comp    = (const float*)d_in[4];
    const float* self_w    = (const float*)d_in[5];
    const float* A_w       = (const float*)d_in[6];
    const float* A_b       = (const float*)d_in[7];
    const float* B_w       = (const float*)d_in[8];
    const float* B_b       = (const float*)d_in[9];
    const float* attn_emb  = (const float*)d_in[10];
    const int*   idx       = (const int*)d_in[11];
    const int*   edge_src  = (const int*)d_in[12];
    const int*   edge_dst  = (const int*)d_in[13];
    const int*   edge_type = (const int*)d_in[14];
    float* out = (float*)d_out;

    // workspace layout
    float* F      = (float*)d_ws;
    float* relw   = F;                       // 16384 f32
    float* aproj  = F + 16384;               // 512 f32
    int*   counts = (int*)(F + 16896);       // 16
    int*   off    = counts + 16;             // 17
    int*   cursor = counts + 33;             // 16
    int*   ssrc   = (int*)d_ws + 17408;      // NE
    int*   sdst   = ssrc + NE;               // NE

    // zero output (agg region must start at 0) and histogram bins
    hipMemsetAsync(d_out, 0, (size_t)out_size * sizeof(float), stream);
    hipMemsetAsync(counts, 0, NR * sizeof(int), stream);

    k_prep<<<64, 256, 0, stream>>>(weight, w_comp, A_w, A_b, attn_emb, relw, aproj);
    k_init<<<(NN + 255) / 256, 256, 0, stream>>>(feat, embed, transform, idx, out);
    k_hist<<<512, 256, 0, stream>>>(edge_type, counts);
    k_prefix<<<1, 64, 0, stream>>>(counts, off, cursor);
    k_scatter<<<512, 256, 0, stream>>>(edge_src, edge_dst, edge_type, cursor, ssrc, sdst);
    dim3 g6(16, 64);
    k_edge<<<g6, 256, 0, stream>>>(out, relw, aproj, A_w, B_w, B_b, off, ssrc, sdst, out);
    k_final<<<(NN + 255) / 256, 256, 0, stream>>>(self_w, out);
}

// Round 2
// 639.519 us; speedup vs baseline: 2.3812x; 2.3812x over previous
//
#include <hip/hip_runtime.h>
#include <math.h>

#define NN 50000
#define NE 800000
#define NR 16

#define BS 512        // edges (and threads) per k_edge_f block
#define NLDS 64       // LDS accumulator rows (nodes) per block
#define WSTR 1032     // W LDS stride per type (floats): 4128 B, 16B-aligned, bank shift 8/type
#define ASTR 36       // aproj LDS stride per type

// ---------------------------------------------------------------------------
// K1: rel_w[r,i,o] = sum_b w_comp[r,b] * weight[b,i,o]          (16x32x32)
//     aproj[t,j]  = A_b[j] + sum_k attn_emb[t,k] * A_w[64+k, j] (16x32)
// ---------------------------------------------------------------------------
__global__ void k_prep(const float* __restrict__ weight, const float* __restrict__ w_comp,
                       const float* __restrict__ A_w, const float* __restrict__ A_b,
                       const float* __restrict__ attn_emb,
                       float* __restrict__ relw, float* __restrict__ aproj) {
    int gid = blockIdx.x * blockDim.x + threadIdx.x;
    if (gid < 16 * 1024) {
        int r = gid >> 10, rest = gid & 1023;
        float acc = 0.f;
#pragma unroll
        for (int b = 0; b < 4; b++) acc += w_comp[r * 4 + b] * weight[b * 1024 + rest];
        relw[gid] = acc;
    }
    if (gid < 16 * 32) {
        int t = gid >> 5, j = gid & 31;
        float acc = A_b[j];
#pragma unroll
        for (int k = 0; k < 32; k++) acc += attn_emb[t * 32 + k] * A_w[(64 + k) * 32 + j];
        aproj[gid] = acc;
    }
}

// ---------------------------------------------------------------------------
// K2: init_fea[i,:] = concat(feat[i], embed[idx[i]]) @ T ; store to out[i,0,:]
// ---------------------------------------------------------------------------
__global__ void k_init(const float* __restrict__ feat, const float* __restrict__ emb,
                       const float* __restrict__ T, const int* __restrict__ idx,
                       float* __restrict__ out) {
    int i = blockIdx.x * blockDim.x + threadIdx.x;
    if (i >= NN) return;
    float v[32], acc[32];
#pragma unroll
    for (int o = 0; o < 32; o++) acc[o] = 0.f;
    const float4* fp = (const float4*)(feat + (size_t)i * 32);
#pragma unroll
    for (int q = 0; q < 8; q++) {
        float4 f = fp[q];
        v[4 * q] = f.x; v[4 * q + 1] = f.y; v[4 * q + 2] = f.z; v[4 * q + 3] = f.w;
    }
#pragma unroll
    for (int d = 0; d < 32; d++) {
        float xd = v[d];
#pragma unroll
        for (int o = 0; o < 32; o++) acc[o] += xd * T[d * 32 + o];
    }
    int row = idx[i];
    const float4* ep = (const float4*)(emb + (size_t)row * 32);
#pragma unroll
    for (int q = 0; q < 8; q++) {
        float4 f = ep[q];
        v[4 * q] = f.x; v[4 * q + 1] = f.y; v[4 * q + 2] = f.z; v[4 * q + 3] = f.w;
    }
#pragma unroll
    for (int d = 0; d < 32; d++) {
        float xd = v[d];
#pragma unroll
        for (int o = 0; o < 32; o++) acc[o] += xd * T[(32 + d) * 32 + o];
    }
    float4* op = (float4*)(out + (size_t)i * 64);
#pragma unroll
    for (int q = 0; q < 8; q++) {
        float4 f;
        f.x = acc[4 * q]; f.y = acc[4 * q + 1]; f.z = acc[4 * q + 2]; f.w = acc[4 * q + 3];
        op[q] = f;
    }
}

// ---------------------------------------------------------------------------
// K3: in-degree histogram over dst (50K bins, plain global int atomics)
// ---------------------------------------------------------------------------
__global__ void k_hist_dst(const int* __restrict__ ed, int* __restrict__ counts) {
    int e = blockIdx.x * blockDim.x + threadIdx.x;
    if (e < NE) atomicAdd(&counts[ed[e]], 1);
}

// ---------------------------------------------------------------------------
// K4: single-block exclusive scan of 50K counts -> row_off (CSR) + cursor
// 1024 threads x 49 sequential items + LDS Hillis-Steele over thread sums.
// ---------------------------------------------------------------------------
__global__ void __launch_bounds__(1024) k_scan_dst(const int* __restrict__ counts,
                                                   int* __restrict__ row_off,
                                                   int* __restrict__ cursor) {
    __shared__ int ls[1024];
    const int ITEMS = 49;
    int tid = threadIdx.x;
    int base = tid * ITEMS;
    int s = 0;
    for (int k = 0; k < ITEMS; k++) {
        int i = base + k;
        if (i < NN) s += counts[i];
    }
    ls[tid] = s;
    __syncthreads();
    for (int off = 1; off < 1024; off <<= 1) {
        int v = (tid >= off) ? ls[tid - off] : 0;
        __syncthreads();
        ls[tid] += v;
        __syncthreads();
    }
    int excl = (tid == 0) ? 0 : ls[tid - 1];
    for (int k = 0; k < ITEMS; k++) {
        int i = base + k;
        if (i < NN) {
            row_off[i] = excl;
            cursor[i] = excl;
            excl += counts[i];
        }
    }
    if (tid == 1023) row_off[NN] = excl;   // == NE
}

// ---------------------------------------------------------------------------
// K5: scatter edges into dst-sorted arrays (src, dst, type)
// ---------------------------------------------------------------------------
__global__ void k_scatter_dst(const int* __restrict__ es, const int* __restrict__ ed,
                              const int* __restrict__ et, int* __restrict__ cursor,
                              int* __restrict__ ssrc, int* __restrict__ sdst,
                              int* __restrict__ stype) {
    int e = blockIdx.x * blockDim.x + threadIdx.x;
    if (e < NE) {
        int d = ed[e];
        int p = atomicAdd(&cursor[d], 1);
        ssrc[p] = es[e];
        sdst[p] = d;
        stype[p] = et[e];
    }
}

// ---------------------------------------------------------------------------
// K6: fused edge kernel over dst-sorted edges. Block owns edges [b*BS,(b+1)*BS).
// W/aproj staged in LDS (per-lane type); A_w wave-uniform -> SGPR-streamed.
// a*msg accumulated into 64-node LDS accumulator (ds_add_f32); writeback:
// fully-owned nodes -> plain float4 store, boundary/overflow -> global atomic.
// ---------------------------------------------------------------------------
__global__ void __launch_bounds__(BS) k_edge_f(
    const float* __restrict__ outr, const float* __restrict__ relw,
    const float* __restrict__ aproj, const float* __restrict__ A_w,
    const float* __restrict__ B_w, const float* __restrict__ B_b,
    const int* __restrict__ row_off, const int* __restrict__ ssrc,
    const int* __restrict__ sdst, const int* __restrict__ stype,
    float* __restrict__ outw) {
    __shared__ float Wl[16 * WSTR];    // 66048 B
    __shared__ float Al[16 * ASTR];    // 2304 B
    __shared__ float acc[NLDS * 33];   // 8448 B
    const int tid = threadIdx.x;

    for (int i = tid; i < 16 * 1024; i += BS) {
        int t = i >> 10, r = i & 1023;
        Wl[t * WSTR + r] = relw[i];
    }
    for (int i = tid; i < 16 * 32; i += BS) {
        int t = i >> 5, j = i & 31;
        Al[t * ASTR + j] = aproj[i];
    }
    for (int i = tid; i < NLDS * 33; i += BS) acc[i] = 0.f;
    __syncthreads();

    const int e0 = blockIdx.x * BS;
    const int e1 = min(e0 + BS, NE);
    const int v_lo = sdst[e0];
    const float bb = B_b[0];

    int e = e0 + tid;
    if (e < e1) {
        int src = ssrc[e], dst = sdst[e], t = stype[e];
        const float* Wt = &Wl[t * WSTR];
        const float* AP = &Al[t * ASTR];
        float v[32], msg[32], hid[32];
        const float4* xp = (const float4*)(outr + (size_t)src * 64);
#pragma unroll
        for (int q = 0; q < 8; q++) {
            float4 f = xp[q];
            v[4 * q] = f.x; v[4 * q + 1] = f.y; v[4 * q + 2] = f.z; v[4 * q + 3] = f.w;
        }
#pragma unroll
        for (int o = 0; o < 32; o++) msg[o] = 0.f;
#pragma unroll
        for (int j = 0; j < 32; j++) hid[j] = AP[j];
#pragma unroll
        for (int d = 0; d < 32; d++) {
            float xd = v[d];
#pragma unroll
            for (int o = 0; o < 32; o++) msg[o] += xd * Wt[d * 32 + o];
#pragma unroll
            for (int j = 0; j < 32; j++) hid[j] += xd * A_w[d * 32 + j];
        }
        const float4* yp = (const float4*)(outr + (size_t)dst * 64);
#pragma unroll
        for (int q = 0; q < 8; q++) {
            float4 f = yp[q];
            v[4 * q] = f.x; v[4 * q + 1] = f.y; v[4 * q + 2] = f.z; v[4 * q + 3] = f.w;
        }
#pragma unroll
        for (int d = 0; d < 32; d++) {
            float yd = v[d];
#pragma unroll
            for (int j = 0; j < 32; j++) hid[j] += yd * A_w[(32 + d) * 32 + j];
        }
        float z = bb;
#pragma unroll
        for (int j = 0; j < 32; j++) z += fmaxf(hid[j], 0.f) * B_w[j];
        float a = 1.f / (1.f + __expf(-z));
        int dl = dst - v_lo;
        if (dl < NLDS) {
            float* ap2 = &acc[dl * 33];
#pragma unroll
            for (int o = 0; o < 32; o++) atomicAdd(&ap2[o], a * msg[o]);
        } else {
            float* gp = outw + (size_t)dst * 64 + 32;
#pragma unroll
            for (int o = 0; o < 32; o++) unsafeAtomicAdd(gp + o, a * msg[o]);
        }
    }
    __syncthreads();

    // writeback: thread -> (row r, col chunk c)
    int r = tid >> 3, c = (tid & 7) * 4;
    int vtx = v_lo + r;
    if (vtx < NN) {
        int rs = row_off[vtx], re = row_off[vtx + 1];
        if (rs < e1 && re > e0 && re > rs) {      // node has edges in my range
            float a0 = acc[r * 33 + c + 0];
            float a1 = acc[r * 33 + c + 1];
            float a2 = acc[r * 33 + c + 2];
            float a3 = acc[r * 33 + c + 3];
            float* gp = outw + (size_t)vtx * 64 + 32 + c;
            if (rs >= e0 && re <= e1) {           // fully owned -> plain store
                float4 f; f.x = a0; f.y = a1; f.z = a2; f.w = a3;
                *(float4*)gp = f;
            } else {                              // boundary -> atomic partial
                unsafeAtomicAdd(gp + 0, a0);
                unsafeAtomicAdd(gp + 1, a1);
                unsafeAtomicAdd(gp + 2, a2);
                unsafeAtomicAdd(gp + 3, a3);
            }
        }
    }
}

// ---------------------------------------------------------------------------
// K7: h = relu(init_fea @ self_loop_W + agg), in place on out[:,1,:]
// ---------------------------------------------------------------------------
__global__ void k_final(const float* __restrict__ S, float* __restrict__ out) {
    int i = blockIdx.x * blockDim.x + threadIdx.x;
    if (i >= NN) return;
    float v[32], acc[32];
    const float4* xp = (const float4*)(out + (size_t)i * 64);
#pragma unroll
    for (int q = 0; q < 8; q++) {
        float4 f = xp[q];
        v[4 * q] = f.x; v[4 * q + 1] = f.y; v[4 * q + 2] = f.z; v[4 * q + 3] = f.w;
    }
    const float4* ap = (const float4*)(out + (size_t)i * 64 + 32);
#pragma unroll
    for (int q = 0; q < 8; q++) {
        float4 f = ap[q];
        acc[4 * q] = f.x; acc[4 * q + 1] = f.y; acc[4 * q + 2] = f.z; acc[4 * q + 3] = f.w;
    }
#pragma unroll
    for (int d = 0; d < 32; d++) {
        float xd = v[d];
#pragma unroll
        for (int o = 0; o < 32; o++) acc[o] += xd * S[d * 32 + o];
    }
    float4* op = (float4*)(out + (size_t)i * 64 + 32);
#pragma unroll
    for (int q = 0; q < 8; q++) {
        float4 f;
        f.x = fmaxf(acc[4 * q], 0.f);
        f.y = fmaxf(acc[4 * q + 1], 0.f);
        f.z = fmaxf(acc[4 * q + 2], 0.f);
        f.w = fmaxf(acc[4 * q + 3], 0.f);
        op[q] = f;
    }
}

extern "C" void kernel_launch(void* const* d_in, const int* in_sizes, int n_in,
                              void* d_out, int out_size, void* d_ws, size_t ws_size,
                              hipStream_t stream) {
    const float* feat      = (const float*)d_in[0];
    const float* embed     = (const float*)d_in[1];
    const float* transform = (const float*)d_in[2];
    const float* weight    = (const float*)d_in[3];
    const float* w_comp    = (const float*)d_in[4];
    const float* self_w    = (const float*)d_in[5];
    const float* A_w       = (const float*)d_in[6];
    const float* A_b       = (const float*)d_in[7];
    const float* B_w       = (const float*)d_in[8];
    const float* B_b       = (const float*)d_in[9];
    const float* attn_emb  = (const float*)d_in[10];
    const int*   idx       = (const int*)d_in[11];
    const int*   edge_src  = (const int*)d_in[12];
    const int*   edge_dst  = (const int*)d_in[13];
    const int*   edge_type = (const int*)d_in[14];
    float* out = (float*)d_out;

    // workspace layout (int/float units from base)
    float* relw      = (float*)d_ws;               // 16384
    float* aproj     = relw + 16384;               // 512
    int*   counts    = (int*)(relw + 16896);       // 50000
    int*   row_off   = counts + 50000;             // 50001
    int*   cursor    = row_off + 50001;            // 50000
    int*   ssrc      = (int*)d_ws + 166912;        // NE
    int*   sdst      = ssrc + NE;                  // NE
    int*   stype     = sdst + NE;                  // NE  (total ~10.3 MB)

    // zero output (agg region + zero-degree nodes) and histogram bins
    hipMemsetAsync(d_out, 0, (size_t)out_size * sizeof(float), stream);
    hipMemsetAsync(counts, 0, NN * sizeof(int), stream);

    k_prep<<<64, 256, 0, stream>>>(weight, w_comp, A_w, A_b, attn_emb, relw, aproj);
    k_init<<<(NN + 255) / 256, 256, 0, stream>>>(feat, embed, transform, idx, out);
    k_hist_dst<<<(NE + 255) / 256, 256, 0, stream>>>(edge_dst, counts);
    k_scan_dst<<<1, 1024, 0, stream>>>(counts, row_off, cursor);
    k_scatter_dst<<<(NE + 255) / 256, 256, 0, stream>>>(edge_src, edge_dst, edge_type,
                                                        cursor, ssrc, sdst, stype);
    k_edge_f<<<(NE + BS - 1) / BS, BS, 0, stream>>>(out, relw, aproj, A_w, B_w, B_b,
                                                    row_off, ssrc, sdst, stype, out);
    k_final<<<(NN + 255) / 256, 256, 0, stream>>>(self_w, out);
}